// Round 1
// 1312.494 us; speedup vs baseline: 1.2293x; 1.2293x over previous
//
#include <hip/hip_runtime.h>
#include <hip/hip_bf16.h>
#include <math.h>

// ---------- types ----------
typedef __attribute__((ext_vector_type(4))) float  float4v;
typedef __attribute__((ext_vector_type(4))) unsigned short ushort4v;
typedef __attribute__((ext_vector_type(8))) __bf16 bf16x8;

typedef __attribute__((address_space(3))) unsigned int       lds_u32;
typedef const __attribute__((address_space(1))) unsigned int glb_u32;

#define BB   8192
#define NN   4
#define DD   2048
#define ND   8192   // N*D
#define DFF  8192
#define EPSF 1.1920928955078125e-07f
#define RPB  4      // rows per block in row_stats

__device__ __forceinline__ unsigned short f2bf(float f) {
  union { float f; unsigned int u; } v; v.f = f;
  unsigned int u = v.u;
  u += 0x7FFFu + ((u >> 16) & 1u);   // round-to-nearest-even
  return (unsigned short)(u >> 16);
}

// ---------------------------------------------------------------------------
// Kernel 1: per-row RMS stats + xn@theta_{pre,post,res} + sigmoid + sinkhorn
// ---------------------------------------------------------------------------
__global__ __launch_bounds__(256) void row_stats_kernel(
    const float* __restrict__ x, const float* __restrict__ w,
    const float* __restrict__ th_pre, const float* __restrict__ th_post,
    const float* __restrict__ th_res,
    const float* __restrict__ a_pre, const float* __restrict__ a_post,
    const float* __restrict__ a_res,
    const float* __restrict__ b_pre, const float* __restrict__ b_post,
    const float* __restrict__ b_res,
    float* __restrict__ Hpre, float* __restrict__ Hpost, float* __restrict__ Hres)
{
  const int b0 = blockIdx.x * RPB;
  const int t = threadIdx.x;
  const float* xr = x + (size_t)b0 * ND;

  float acc[RPB][25];
#pragma unroll
  for (int r = 0; r < RPB; ++r)
#pragma unroll
    for (int c = 0; c < 25; ++c) acc[r][c] = 0.0f;

  const float4v* tp = (const float4v*)th_pre;
  const float4v* tq = (const float4v*)th_post;
  const float4v* tr = (const float4v*)th_res;

  for (int j = 0; j < ND / 256; ++j) {
    int i = j * 256 + t;
    float wv = w[i];
    float4v p  = tp[i];
    float4v q  = tq[i];
    float4v r0 = tr[i*4+0], r1 = tr[i*4+1], r2 = tr[i*4+2], r3 = tr[i*4+3];
#pragma unroll
    for (int r = 0; r < RPB; ++r) {
      float xv = xr[(size_t)r * ND + i];
      float xw = xv * wv;
      acc[r][0] += xv * xv;
      acc[r][1] += xw * p.x;  acc[r][2] += xw * p.y;
      acc[r][3] += xw * p.z;  acc[r][4] += xw * p.w;
      acc[r][5] += xw * q.x;  acc[r][6] += xw * q.y;
      acc[r][7] += xw * q.z;  acc[r][8] += xw * q.w;
      acc[r][9]  += xw * r0.x; acc[r][10] += xw * r0.y;
      acc[r][11] += xw * r0.z; acc[r][12] += xw * r0.w;
      acc[r][13] += xw * r1.x; acc[r][14] += xw * r1.y;
      acc[r][15] += xw * r1.z; acc[r][16] += xw * r1.w;
      acc[r][17] += xw * r2.x; acc[r][18] += xw * r2.y;
      acc[r][19] += xw * r2.z; acc[r][20] += xw * r2.w;
      acc[r][21] += xw * r3.x; acc[r][22] += xw * r3.y;
      acc[r][23] += xw * r3.z; acc[r][24] += xw * r3.w;
    }
  }

#pragma unroll
  for (int r = 0; r < RPB; ++r)
#pragma unroll
    for (int c = 0; c < 25; ++c) {
#pragma unroll
      for (int off = 32; off > 0; off >>= 1)
        acc[r][c] += __shfl_down(acc[r][c], off);
    }

  __shared__ float red[4][RPB * 25];
  __shared__ float s[RPB * 25];
  int lane = t & 63, wv4 = t >> 6;
  if (lane == 0) {
#pragma unroll
    for (int r = 0; r < RPB; ++r)
#pragma unroll
      for (int c = 0; c < 25; ++c) red[wv4][r * 25 + c] = acc[r][c];
  }
  __syncthreads();
  if (t < RPB * 25) s[t] = red[0][t] + red[1][t] + red[2][t] + red[3][t];
  __syncthreads();

  if (t < RPB) {
    const int b = b0 + t;
    const float* sv = &s[t * 25];
    float scale = rsqrtf(sv[0] / (float)ND + EPSF);
    float ap = a_pre[0], apo = a_post[0], ar = a_res[0];

#pragma unroll
    for (int n = 0; n < 4; ++n) {
      float vpre = ap * sv[1 + n] * scale + b_pre[n];
      Hpre[b * 4 + n] = 1.0f / (1.0f + expf(-vpre));
      float vpost = apo * sv[5 + n] * scale + b_post[n];
      Hpost[b * 4 + n] = 2.0f / (1.0f + expf(-vpost));
    }

    float m[16];
#pragma unroll
    for (int k = 0; k < 16; ++k)
      m[k] = expf(ar * sv[9 + k] * scale + b_res[k]);

    for (int it = 0; it < 20; ++it) {
#pragma unroll
      for (int n = 0; n < 4; ++n) {
        float rs = m[n*4] + m[n*4+1] + m[n*4+2] + m[n*4+3];
        float inv = 1.0f / rs;
        m[n*4] *= inv; m[n*4+1] *= inv; m[n*4+2] *= inv; m[n*4+3] *= inv;
      }
#pragma unroll
      for (int c = 0; c < 4; ++c) {
        float cs = m[c] + m[4+c] + m[8+c] + m[12+c];
        float inv = 1.0f / cs;
        m[c] *= inv; m[4+c] *= inv; m[8+c] *= inv; m[12+c] *= inv;
      }
    }
#pragma unroll
    for (int k = 0; k < 16; ++k) Hres[b * 16 + k] = m[k];
  }
}

// ---------------------------------------------------------------------------
// Kernel 2: x_pre[b,d] = sum_n Hpre[b,n]*x[b,n,d], stored as bf16
// ---------------------------------------------------------------------------
__global__ __launch_bounds__(256) void xpre_kernel(
    const float* __restrict__ x, const float* __restrict__ Hpre,
    unsigned short* __restrict__ xpre)
{
  int b = blockIdx.x, t = threadIdx.x;
  float h0 = Hpre[b*4+0], h1 = Hpre[b*4+1], h2 = Hpre[b*4+2], h3 = Hpre[b*4+3];
  const float4v* xb = (const float4v*)(x + (size_t)b * ND);
  ushort4v* ob = (ushort4v*)(xpre + (size_t)b * DD);
#pragma unroll
  for (int g = 0; g < 2; ++g) {
    int i = g * 256 + t;
    float4v v = h0 * xb[i] + h1 * xb[512 + i] + h2 * xb[1024 + i] + h3 * xb[1536 + i];
    ushort4v o;
    o.x = f2bf(v.x); o.y = f2bf(v.y); o.z = f2bf(v.z); o.w = f2bf(v.w);
    ob[i] = o;
  }
}

// ---------------------------------------------------------------------------
// Kernel 3: transpose + fp32->bf16 convert: W[K][N] -> Wt[N][K]
// ---------------------------------------------------------------------------
__global__ __launch_bounds__(256) void transpose_bf16_kernel(
    const float* __restrict__ W, unsigned short* __restrict__ Wt, int K, int N)
{
  __shared__ float tile[64][65];
  int tx = threadIdx.x & 63, ty = threadIdx.x >> 6;
  int k0 = blockIdx.y * 64, n0 = blockIdx.x * 64;
#pragma unroll
  for (int r = 0; r < 16; ++r) {
    int kk = r * 4 + ty;
    tile[kk][tx] = W[(size_t)(k0 + kk) * N + n0 + tx];
  }
  __syncthreads();
#pragma unroll
  for (int r = 0; r < 16; ++r) {
    int nn = r * 4 + ty;
    Wt[(size_t)(n0 + nn) * K + k0 + tx] = f2bf(tile[tx][nn]);
  }
}

// ---------------------------------------------------------------------------
// MFMA bf16 GEMM — 256x256 tile, BK=64, 8-phase counted-vmcnt schedule
// (m201/m204 template: T1 XCD swizzle + T2 st-XOR swizzle + T3/T4 8-phase
//  counted vmcnt + T5 setprio). 512 threads = 8 waves (2M x 4N), per-wave
//  output 128x64, acc[8][4] f32x4. LDS 128 KiB: As/Bs 2-dbuf x 256x64 bf16.
//
// Swizzle (both-sides, rule #21): physical 16B slot p within a 128B row holds
// logical slot p ^ (row&7). Staging: linear global_load_lds dest, per-lane
// global source pre-permuted (slot = (lane&7)^(lane>>3)). ds_read_b128:
// byte = row*128 + (((ks*4+q) ^ (rr&7))<<4) -> each 8-lane group covers all
// 32 banks exactly once (2-way max across the wave = free, m136).
//
// Stage ledger (1 half-tile = 2 loads/thread per phase; buf = tile%2):
//  P1: A-h0(2i+1)->b1   P2: A-h1(2i+1)->b1   P3: B-h0(2i+2)->b0
//  P4: B-h1(2i+2)->b0 +vmcnt(4)              P5: A-h0(2i+2)->b0
//  P6: A-h1(2i+2)->b0   P7: B-h0(2i+3)->b1   P8: B-h1(2i+3)->b1 +vmcnt(4)
// WAR: A-halves of a buffer free after that tile's P3, B-halves after P2 —
// every stage lands >=2 barrier-separated phases after the last ds_read.
// RAW: vmcnt(4) leaves exactly the 2 newest half-tiles in flight; the next
// tile's 8 loads are always older -> retired before its first ds_read.
// ---------------------------------------------------------------------------

#define STAGE_A(bb, h, kt) do { \
    const unsigned short* _s = baseA + (size_t)((h) * 128) * KD + (size_t)(kt) * 64; \
    __builtin_amdgcn_global_load_lds((glb_u32*)_s, \
        (lds_u32*)(ldsA + ((bb) << 14) + ((h) << 13)), 16, 0, 0); \
    __builtin_amdgcn_global_load_lds((glb_u32*)(_s + (size_t)64 * KD), \
        (lds_u32*)(ldsA + ((bb) << 14) + ((h) << 13) + 4096), 16, 0, 0); \
  } while (0)

#define STAGE_B(bb, h, kt) do { \
    const unsigned short* _s = baseB + (size_t)((h) * 128) * KD + (size_t)(kt) * 64; \
    __builtin_amdgcn_global_load_lds((glb_u32*)_s, \
        (lds_u32*)(ldsB + ((bb) << 14) + ((h) << 13)), 16, 0, 0); \
    __builtin_amdgcn_global_load_lds((glb_u32*)(_s + (size_t)64 * KD), \
        (lds_u32*)(ldsB + ((bb) << 14) + ((h) << 13) + 4096), 16, 0, 0); \
  } while (0)

#define LDSA(buf, mi, ks) (*reinterpret_cast<const bf16x8*>( \
    AsB + ((buf) << 15) + aBase + ((mi) << 11) + (s0 ^ ((ks) << 6))))
#define LDSB(buf, ni, ks) (*reinterpret_cast<const bf16x8*>( \
    BsB + ((buf) << 15) + bBase + ((ni) << 11) + (s0 ^ ((ks) << 6))))

#define RD_A0(buf) { _Pragma("unroll") for (int mi = 0; mi < 4; ++mi) { \
    _Pragma("unroll") for (int ks = 0; ks < 2; ++ks) a0[mi][ks] = LDSA(buf, mi, ks); } }
#define RD_A1(buf) { _Pragma("unroll") for (int mi = 0; mi < 4; ++mi) { \
    _Pragma("unroll") for (int ks = 0; ks < 2; ++ks) a1[mi][ks] = LDSA(buf, 4 + mi, ks); } }
#define RD_B0(buf) { _Pragma("unroll") for (int ni = 0; ni < 2; ++ni) { \
    _Pragma("unroll") for (int ks = 0; ks < 2; ++ks) b0[ni][ks] = LDSB(buf, ni, ks); } }
#define RD_B1(buf) { _Pragma("unroll") for (int ni = 0; ni < 2; ++ni) { \
    _Pragma("unroll") for (int ks = 0; ks < 2; ++ks) b1[ni][ks] = LDSB(buf, 2 + ni, ks); } }

#define QUAD(AF, BF, MB, NB) { \
    __builtin_amdgcn_s_setprio(1); \
    _Pragma("unroll") for (int m = 0; m < 4; ++m) { \
      _Pragma("unroll") for (int n = 0; n < 2; ++n) { \
        _Pragma("unroll") for (int ks = 0; ks < 2; ++ks) { \
          acc[(MB) + m][(NB) + n] = __builtin_amdgcn_mfma_f32_16x16x32_bf16( \
              AF[m][ks], BF[n][ks], acc[(MB) + m][(NB) + n], 0, 0, 0); } } } \
    __builtin_amdgcn_s_setprio(0); }

#define SBAR() do { __builtin_amdgcn_sched_barrier(0); \
    __builtin_amdgcn_s_barrier(); __builtin_amdgcn_sched_barrier(0); } while (0)
#define LGKM0() do { asm volatile("s_waitcnt lgkmcnt(0)" ::: "memory"); \
    __builtin_amdgcn_sched_barrier(0); } while (0)
#define VMC4() do { asm volatile("s_waitcnt vmcnt(4)" ::: "memory"); } while (0)

template<int EPI, int KD, int NDim>
__global__ __launch_bounds__(512, 2) void gemm256(
    const unsigned short* __restrict__ A, const unsigned short* __restrict__ Bt,
    const float* __restrict__ bias, void* __restrict__ Cout)
{
  __shared__ __align__(16) unsigned short As[2 * 16384];   // 64 KiB
  __shared__ __align__(16) unsigned short Bs[2 * 16384];   // 64 KiB

  const int t = threadIdx.x;
  const int lane = t & 63, wave = t >> 6;
  const int wm = wave >> 2, wn = wave & 3;     // 2M x 4N wave grid

  constexpr int NBX = NDim / 256;
  constexpr int NWG = NBX * (BB / 256);
  constexpr int NT  = KD / 64;
  constexpr int NIT = NT / 2;

  // T1: bijective XCD swizzle (NWG % 8 == 0 for both instantiations)
  const int lin = blockIdx.y * NBX + blockIdx.x;
  const int swz = (lin & 7) * (NWG / 8) + (lin >> 3);
  const int m0 = (swz / NBX) * 256;
  const int n0 = (swz % NBX) * 256;

  // staging: lane l covers (row = +l/8, physical slot = l&7); the global
  // source fetches logical slot (l&7)^(l>>3)  [= phys ^ (row&7)]
  const int l8 = lane >> 3, l7 = lane & 7;
  const unsigned short* baseA = A  + (size_t)(m0 + wave * 8 + l8) * KD + ((l7 ^ l8) << 3);
  const unsigned short* baseB = Bt + (size_t)(n0 + wave * 8 + l8) * KD + ((l7 ^ l8) << 3);
  unsigned short* ldsA = &As[wave * 512];
  unsigned short* ldsB = &Bs[wave * 512];

  // ds_read addressing
  const int rr = lane & 15, qq = lane >> 4;
  const int s0 = (qq ^ (rr & 7)) << 4;          // swizzled byte-slot for ks=0
  const char* AsB = (const char*)As;
  const char* BsB = (const char*)Bs;
  const int aBase = (wm << 14) + (rr << 7);     // half-select + row byte
  const int bBase = (wn << 13) + (rr << 7);     // = (wn>>1)<<14 | (wn&1)<<13

  float4v acc[8][4];
#pragma unroll
  for (int i = 0; i < 8; ++i)
#pragma unroll
    for (int j = 0; j < 4; ++j) acc[i][j] = (float4v)0.0f;

  bf16x8 a0[4][2], a1[4][2], b0[2][2], b1[2][2];

  // ---- prologue: tile0 (all 4 halves) + tile1 B-halves; wait tile0 landed
  STAGE_B(0, 0, 0); STAGE_B(0, 1, 0);
  STAGE_A(0, 0, 0); STAGE_A(0, 1, 0);
  STAGE_B(1, 0, 1); STAGE_B(1, 1, 1);
  VMC4();
  SBAR();

#pragma unroll 1
  for (int i = 0; i < NIT; ++i) {
    const int t1 = 2 * i + 1;                               // always < NT
    const int t2 = (2 * i + 2 < NT) ? 2 * i + 2 : NT - 1;   // clamped re-stage
    const int t3 = (2 * i + 3 < NT) ? 2 * i + 3 : NT - 1;   // keeps vmcnt ledger

    // ---- P1 (tile 2i, buf0): Qa = acc[0..3][0..1]
    RD_A0(0); RD_B0(0);
    STAGE_A(1, 0, t1);
    SBAR(); LGKM0();
    QUAD(a0, b0, 0, 0);
    SBAR();
    // ---- P2: Qc = acc[0..3][2..3]
    RD_B1(0);
    STAGE_A(1, 1, t1);
    SBAR(); LGKM0();
    QUAD(a0, b1, 0, 2);
    SBAR();
    // ---- P3: Qb = acc[4..7][0..1]
    RD_A1(0);
    STAGE_B(0, 0, t2);
    SBAR(); LGKM0();
    QUAD(a1, b0, 4, 0);
    SBAR();
    // ---- P4: Qd = acc[4..7][2..3]; counted vmcnt before buffer switch
    STAGE_B(0, 1, t2);
    SBAR(); LGKM0();
    QUAD(a1, b1, 4, 2);
    VMC4();
    SBAR();
    // ---- P5 (tile 2i+1, buf1)
    RD_A0(1); RD_B0(1);
    STAGE_A(0, 0, t2);
    SBAR(); LGKM0();
    QUAD(a0, b0, 0, 0);
    SBAR();
    // ---- P6
    RD_B1(1);
    STAGE_A(0, 1, t2);
    SBAR(); LGKM0();
    QUAD(a0, b1, 0, 2);
    SBAR();
    // ---- P7
    RD_A1(1);
    STAGE_B(1, 0, t3);
    SBAR(); LGKM0();
    QUAD(a1, b0, 4, 0);
    SBAR();
    // ---- P8
    STAGE_B(1, 1, t3);
    SBAR(); LGKM0();
    QUAD(a1, b1, 4, 2);
    VMC4();
    SBAR();
  }

  // ---- epilogue — C/D: col=lane&15, row=(lane>>4)*4+reg (m89/m91 verified)
  const int cl = lane & 15;
  const int colB = n0 + wn * 64 + cl;
  const int rowB = m0 + wm * 128 + (lane >> 4) * 4;
  float bv[4];
#pragma unroll
  for (int ni = 0; ni < 4; ++ni) bv[ni] = bias[colB + ni * 16];
#pragma unroll
  for (int mi = 0; mi < 8; ++mi) {
#pragma unroll
    for (int ni = 0; ni < 4; ++ni) {
#pragma unroll
      for (int r = 0; r < 4; ++r) {
        int row = rowB + mi * 16 + r;
        int col = colB + ni * 16;
        float v = acc[mi][ni][r] + bv[ni];
        if (EPI == 1) {
          v = 0.5f * v * (1.0f + erff(v * 0.70710678118654752f));
          ((unsigned short*)Cout)[(size_t)row * NDim + col] = f2bf(v);
        } else {
          ((float*)Cout)[(size_t)row * NDim + col] = v;
        }
      }
    }
  }
}

#undef STAGE_A
#undef STAGE_B
#undef LDSA
#undef LDSB
#undef RD_A0
#undef RD_A1
#undef RD_B0
#undef RD_B1
#undef QUAD
#undef SBAR
#undef LGKM0
#undef VMC4

// ---------------------------------------------------------------------------
// Kernel 7: out[b,n,d] = Hpost[b,n]*Hbar[b,d] + sum_m Hres[b,n,m]*x[b,m,d]
// ---------------------------------------------------------------------------
__global__ __launch_bounds__(256) void final_kernel(
    const float* __restrict__ x, const float* __restrict__ Hpost,
    const float* __restrict__ Hres, const float* __restrict__ Hbar,
    float* __restrict__ out)
{
  int b = blockIdx.x, t = threadIdx.x;
  float hp[4], hr[16];
#pragma unroll
  for (int n = 0; n < 4; ++n) hp[n] = Hpost[b * 4 + n];
#pragma unroll
  for (int k = 0; k < 16; ++k) hr[k] = Hres[b * 16 + k];

  const float4v* xb = (const float4v*)(x + (size_t)b * ND);
  const float4v* hb = (const float4v*)(Hbar + (size_t)b * DD);
  float4v* ob = (float4v*)(out + (size_t)b * ND);

#pragma unroll
  for (int g = 0; g < 2; ++g) {
    int i = g * 256 + t;
    float4v x0 = xb[i], x1 = xb[512 + i], x2 = xb[1024 + i], x3 = xb[1536 + i];
    float4v hv = hb[i];
#pragma unroll
    for (int n = 0; n < 4; ++n) {
      float4v o = hp[n] * hv
                + hr[n*4+0] * x0 + hr[n*4+1] * x1
                + hr[n*4+2] * x2 + hr[n*4+3] * x3;
      ob[n * 512 + i] = o;
    }
  }
}

// ---------------------------------------------------------------------------
extern "C" void kernel_launch(void* const* d_in, const int* in_sizes, int n_in,
                              void* d_out, int out_size, void* d_ws, size_t ws_size,
                              hipStream_t stream) {
  const float* x       = (const float*)d_in[0];
  const float* rms_w   = (const float*)d_in[1];
  const float* th_pre  = (const float*)d_in[2];
  const float* th_post = (const float*)d_in[3];
  const float* th_res  = (const float*)d_in[4];
  const float* a_pre   = (const float*)d_in[5];
  const float* a_post  = (const float*)d_in[6];
  const float* a_res   = (const float*)d_in[7];
  const float* b_pre   = (const float*)d_in[8];
  const float* b_post  = (const float*)d_in[9];
  const float* b_res   = (const float*)d_in[10];
  const float* W1      = (const float*)d_in[11];
  const float* b1      = (const float*)d_in[12];
  const float* W2      = (const float*)d_in[13];
  const float* b2      = (const float*)d_in[14];
  float* out = (float*)d_out;

  char* ws = (char*)d_ws;
  float* Hpre  = (float*)ws;                 ws += (size_t)BB * 4 * 4;
  float* Hpost = (float*)ws;                 ws += (size_t)BB * 4 * 4;
  float* Hres  = (float*)ws;                 ws += (size_t)BB * 16 * 4;
  unsigned short* xpre = (unsigned short*)ws; ws += (size_t)BB * DD * 2;
  unsigned short* W1t  = (unsigned short*)ws; ws += (size_t)DFF * DD * 2;
  unsigned short* W2t  = (unsigned short*)ws; ws += (size_t)DD * DFF * 2;
  unsigned short* G    = (unsigned short*)ws; ws += (size_t)BB * DFF * 2;
  float* Hbar = (float*)ws;                  ws += (size_t)BB * DD * 4;

  row_stats_kernel<<<dim3(BB / RPB), dim3(256), 0, stream>>>(
      x, rms_w, th_pre, th_post, th_res, a_pre, a_post, a_res,
      b_pre, b_post, b_res, Hpre, Hpost, Hres);

  xpre_kernel<<<dim3(BB), dim3(256), 0, stream>>>(x, Hpre, xpre);

  // W1[K=DD][N=DFF] -> W1t[DFF][DD]
  transpose_bf16_kernel<<<dim3(DFF / 64, DD / 64), dim3(256), 0, stream>>>(
      W1, W1t, DD, DFF);
  // W2[K=DFF][N=DD] -> W2t[DD][DFF]
  transpose_bf16_kernel<<<dim3(DD / 64, DFF / 64), dim3(256), 0, stream>>>(
      W2, W2t, DFF, DD);

  // GEMM1: G = gelu(xpre @ W1 + b1)   [M=BB, N=DFF, K=DD]
  gemm256<1, DD, DFF><<<dim3(DFF / 256, BB / 256), dim3(512), 0, stream>>>(
      xpre, W1t, b1, (void*)G);

  // GEMM2: Hbar = G @ W2 + b2        [M=BB, N=DD, K=DFF]
  gemm256<0, DFF, DD><<<dim3(DD / 256, BB / 256), dim3(512), 0, stream>>>(
      G, W2t, b2, (void*)Hbar);

  final_kernel<<<dim3(BB), dim3(256), 0, stream>>>(x, Hpost, Hres, Hbar, out);
}